// Round 10
// baseline (427.137 us; speedup 1.0000x reference)
//
#include <hip/hip_runtime.h>

typedef __attribute__((ext_vector_type(8))) short short8;
typedef __attribute__((ext_vector_type(4))) short short4v;
typedef __attribute__((ext_vector_type(4))) float float4v;

typedef const __attribute__((address_space(1))) unsigned int* gptr_t;
typedef __attribute__((address_space(3))) unsigned int* lptr_t;

__device__ __forceinline__ unsigned short f2bf(float f) {
  unsigned u = __float_as_uint(f);
  u += 0x7FFFu + ((u >> 16) & 1u);
  return (unsigned short)(u >> 16);
}
__device__ __forceinline__ float bf2f(unsigned short h) {
  return __uint_as_float(((unsigned)h) << 16);
}

// ---------------- weights f32 -> bf16 (all three in one dispatch) ----------------
__global__ __launch_bounds__(256) void cvtW_kernel(const float* __restrict__ Wq,
                                                   const float* __restrict__ Wk,
                                                   const float* __restrict__ Wv,
                                                   unsigned short* __restrict__ wb) {
  int blk = blockIdx.x;
  int r = blk >> 10;
  const float* src = (r == 0) ? Wq : ((r == 1) ? Wk : Wv);
  int t = threadIdx.x;
  int i = (blk & 1023) * 256 + t;
  float4v v = ((const float4v*)src)[i];
  short4v o;
  o[0] = (short)f2bf(v[0]);
  o[1] = (short)f2bf(v[1]);
  o[2] = (short)f2bf(v[2]);
  o[3] = (short)f2bf(v[3]);
  ((short4v*)(wb + (size_t)r * 1048576u))[i] = o;
}

// ---------------- pad-mask compaction: prefix counts + index map (+ zero mean_x) ----------------
__global__ __launch_bounds__(256) void compact_kernel(const int* __restrict__ pad,
                                                      int* __restrict__ jmap,
                                                      int* __restrict__ cntb,
                                                      float* __restrict__ mean_x) {
  int b = blockIdx.x;
  const int* prow = pad + b * 2048;
  int t = threadIdx.x;
  float4v z = {0.f, 0.f, 0.f, 0.f};
  ((float4v*)(mean_x + b * 1024))[t] = z;
  int base = t * 8;
  int ind[8], incl[8];
  int s = 0;
#pragma unroll
  for (int e = 0; e < 8; ++e) {
    ind[e] = (prow[base + e] == 0);
    s += ind[e];
    incl[e] = s;
  }
  int lane = t & 63, wv = t >> 6;
  int v = s;
#pragma unroll
  for (int off = 1; off < 64; off <<= 1) {
    int u = __shfl_up(v, off);
    if (lane >= off) v += u;
  }
  __shared__ int wsum[4];
  if (lane == 63) wsum[wv] = v;
  __syncthreads();
  int wbase = 0;
  for (int w = 0; w < wv; ++w) wbase += wsum[w];
  int excl_base = wbase + v - s;
#pragma unroll
  for (int e = 0; e < 8; ++e) {
    int cnt_i = excl_base + incl[e];
    cntb[b * 2048 + base + e] = cnt_i;
    if (ind[e]) jmap[b * 2048 + cnt_i - 1] = base + e;
  }
}

// ---------------- fused x convert + compacted scatter + xc pad-row zero-fill ----------------
__global__ __launch_bounds__(256) void prep_kernel(const float* __restrict__ x,
                                                   const int* __restrict__ pad,
                                                   const int* __restrict__ cntb,
                                                   unsigned short* __restrict__ xb,
                                                   unsigned short* __restrict__ xc) {
  int i = blockIdx.x, b = blockIdx.y;
  int idx = b * 2048 + i;
  int t = threadIdx.x;
  float4v v = ((const float4v*)(x + (size_t)idx * 1024))[t];
  short4v o;
  o[0] = (short)f2bf(v[0]);
  o[1] = (short)f2bf(v[1]);
  o[2] = (short)f2bf(v[2]);
  o[3] = (short)f2bf(v[3]);
  ((short4v*)(xb + (size_t)idx * 1024))[t] = o;
  if (pad[idx] == 0) {
    int jc = cntb[idx] - 1;
    ((short4v*)(xc + ((size_t)(b * 2048 + jc)) * 1024))[t] = o;
  }
  // zero-fill xc rows [Nc, roundup128(Nc)) — row index i reused as the fill target
  int Nc = cntb[b * 2048 + 2047];
  if (i >= Nc && i < ((Nc + 127) & ~127)) {
    short4v z = {0, 0, 0, 0};
    ((short4v*)(xc + ((size_t)(b * 2048 + i)) * 1024))[t] = z;
  }
}

// ---------------- column-sum of xb per batch (coalesced row-major reads) ----------------
__global__ __launch_bounds__(256) void meanx_kernel(const unsigned short* __restrict__ xb,
                                                    float* __restrict__ mean_x) {
  int iblk = blockIdx.x, b = blockIdx.y;
  int t = threadIdx.x;
  const unsigned short* base = xb + ((size_t)b * 2048 + (size_t)iblk * 64) * 1024 + t * 4;
  float s0 = 0.f, s1 = 0.f, s2 = 0.f, s3 = 0.f;
  for (int r = 0; r < 64; ++r) {
    short4v v = *(const short4v*)(base + (size_t)r * 1024);
    s0 += bf2f(((const unsigned short*)&v)[0]);
    s1 += bf2f(((const unsigned short*)&v)[1]);
    s2 += bf2f(((const unsigned short*)&v)[2]);
    s3 += bf2f(((const unsigned short*)&v)[3]);
  }
  float* mp = mean_x + b * 1024 + t * 4;
  atomicAdd(mp + 0, s0);
  atomicAdd(mp + 1, s1);
  atomicAdd(mp + 2, s2);
  atomicAdd(mp + 3, s3);
}

// ---------------- fixmean = mean_x/2048 @ Wv^T + bv ----------------
__global__ __launch_bounds__(256) void gemv_kernel(const float* __restrict__ mean_x,
                                                   const unsigned short* __restrict__ wv,
                                                   const float* __restrict__ bv,
                                                   float* __restrict__ fixmean) {
  int b = blockIdx.x, dblk = blockIdx.y;
  int d = dblk * 256 + threadIdx.x;
  const unsigned short* wrow = wv + (size_t)d * 1024;
  const float* mx = mean_x + b * 1024;
  float s = 0.f;
  for (int h = 0; h < 1024; h += 8) {
    short8 w = *(const short8*)(wrow + h);
#pragma unroll
    for (int e = 0; e < 8; ++e) s += mx[h + e] * bf2f(((const unsigned short*)&w)[e]);
  }
  fixmean[b * 1024 + d] = s * (1.0f / 2048.0f) + bv[d];
}

// ---------------- bf16 GEMM, C = A @ B^T (round-6 exact engine, 4 waves, 128x128) ----------------
// MODE 0: fused projection q|k|v, grid (24,128), XCD-swizzled
// MODE 1: qk : bf16 out, compacted-causal tile-skip, grid (16,16,8)
// MODE 2: pv : f32 out, K-limit roundup64(cnt), grid (8,16,8)
template <int MODE>
__global__ __launch_bounds__(256, 5) void gemm_bt_kernel(
    const unsigned short* __restrict__ A, const unsigned short* __restrict__ A2,
    const unsigned short* __restrict__ B,
    const float* __restrict__ b1, const float* __restrict__ b2, const float* __restrict__ b3,
    void* __restrict__ C, unsigned short* __restrict__ C2, unsigned short* __restrict__ C3,
    const int* __restrict__ cnt,
    int K, int lda, int ldb, int ldc, size_t sA, size_t sB, size_t sC) {
  int bx = blockIdx.x, by = blockIdx.y, bz = blockIdx.z;
  const unsigned short* Aptr = A;
  if (MODE == 0) {  // nwg = 24*128 = 3072, bijective XCD swizzle
    int wg = by * 24 + bx;
    int s = (wg & 7) * 384 + (wg >> 3);
    bx = s % 24;
    by = s / 24;
    int r = bx >> 3;
    if (r > 0) {
      int b = by >> 4;
      if (((by & 15) << 7) >= cnt[(b << 11) + 2047]) return;
      Aptr = A2;
    }
  }
  int Kend = K;
  if (MODE == 1) {
    int tc = cnt[(bz << 11) + (by * 128 + 127)];
    if (bx * 128 >= tc) return;
  }
  if (MODE == 2) {
    int tc = cnt[(bz << 11) + (by * 128 + 127)];
    Kend = (tc + 63) & ~63;
  }

  __shared__ __align__(16) char lds[32768];
  char* ldsA = lds;
  char* ldsB = lds + 16384;

  int tid = threadIdx.x;
  int wave = tid >> 6, lane = tid & 63;
  int lm = lane & 15, g = lane >> 4;
  int wm = wave >> 1, wn = wave & 1;
  int swl = (lm & 7) << 4;

  float4v acc[4][4];
#pragma unroll
  for (int i = 0; i < 4; ++i)
#pragma unroll
    for (int j = 0; j < 4; ++j) {
      float4v z = {0.f, 0.f, 0.f, 0.f};
      acc[i][j] = z;
    }

  const char* Abase = (const char*)(Aptr + sA * (size_t)bz + (size_t)(by * 128) * (size_t)lda);
  const char* Bbase = (const char*)(B + sB * (size_t)bz + (size_t)(bx * 128) * (size_t)ldb);
  size_t strideA = (size_t)lda * 2u;
  size_t strideB = (size_t)ldb * 2u;

  int Lbase = wave * 1024 + lane * 16;

  for (int kt = 0; kt < Kend; kt += 64) {
#pragma unroll
    for (int c = 0; c < 4; ++c) {
      int L = c * 4096 + Lbase;
      int row = L >> 7;
      int lb = (L & 127) ^ ((row & 7) << 4);  // inverse-swizzled source byte within row
      const char* ga = Abase + (size_t)row * strideA + (size_t)(kt * 2) + lb;
      __builtin_amdgcn_global_load_lds((gptr_t)(const void*)ga,
                                       (lptr_t)(void*)(ldsA + c * 4096 + wave * 1024), 16, 0, 0);
      const char* gb = Bbase + (size_t)row * strideB + (size_t)(kt * 2) + lb;
      __builtin_amdgcn_global_load_lds((gptr_t)(const void*)gb,
                                       (lptr_t)(void*)(ldsB + c * 4096 + wave * 1024), 16, 0, 0);
    }
    __syncthreads();

#pragma unroll
    for (int k0 = 0; k0 < 64; k0 += 32) {
      short8 af[4], bfv[4];
      int b0 = (k0 * 2 + 16 * g) ^ swl;  // contiguous 16B k-chunk (self-consistent permutation)
#pragma unroll
      for (int mi = 0; mi < 4; ++mi) {
        const char* p = ldsA + (wm * 64 + mi * 16 + lm) * 128;
        af[mi] = *(const short8*)(p + b0);
      }
#pragma unroll
      for (int ni = 0; ni < 4; ++ni) {
        const char* p = ldsB + (wn * 64 + ni * 16 + lm) * 128;
        bfv[ni] = *(const short8*)(p + b0);
      }
#pragma unroll
      for (int mi = 0; mi < 4; ++mi)
#pragma unroll
        for (int ni = 0; ni < 4; ++ni)
          acc[mi][ni] =
              __builtin_amdgcn_mfma_f32_16x16x32_bf16(af[mi], bfv[ni], acc[mi][ni], 0, 0, 0);
    }
    __syncthreads();
  }

  // epilogue: C/D layout col = lane&15, row = (lane>>4)*4 + r   [m89-verified]
  int mb = by * 128 + wm * 64 + g * 4;
  int nb = bx * 128 + wn * 64 + lm;
#pragma unroll
  for (int mi = 0; mi < 4; ++mi) {
#pragma unroll
    for (int ni = 0; ni < 4; ++ni) {
      int n = nb + ni * 16;
      float bias = 0.0f;
      if (MODE == 0) {
        int nn = n & 1023;
        int r = n >> 10;
        bias = (r == 0) ? b1[nn] : ((r == 1) ? b2[nn] : b3[nn]);
      }
#pragma unroll
      for (int r4 = 0; r4 < 4; ++r4) {
        int m = mb + mi * 16 + r4;
        float v = acc[mi][ni][r4] + bias;
        if (MODE == 0) {
          int nn = n & 1023;
          int r = n >> 10;
          if (r == 0) {
            ((unsigned short*)C)[(size_t)m * 1024u + nn] = f2bf(v);
          } else if (r == 1) {
            C3[(size_t)m * 1024u + nn] = f2bf(v);
          } else {
            size_t idx = ((size_t)(m >> 11) << 21) + ((size_t)nn << 11) + (size_t)(m & 2047);
            C2[idx] = f2bf(v);
          }
        } else if (MODE == 1) {
          ((unsigned short*)C)[sC * (size_t)bz + (size_t)m * (size_t)ldc + n] = f2bf(v);
        } else {
          ((float*)C)[sC * (size_t)bz + (size_t)m * (size_t)ldc + n] = v;
        }
      }
    }
  }
}

// ---------------- compacted masked softmax, in-place on bf16 scores ----------------
__global__ __launch_bounds__(256) void softmax_kernel(unsigned short* __restrict__ sp,
                                                      const int* __restrict__ cntb) {
  int i = blockIdx.x, b = blockIdx.y;
  int cnt_i = cntb[b * 2048 + i];
  int tcnt = cntb[b * 2048 + (i | 127)];
  int W = (tcnt + 63) & ~63;
  unsigned short* row = sp + ((size_t)b * 2048 + (size_t)i) * 2048;
  int tid = threadIdx.x;
  int j0 = tid * 8;
  bool active = (j0 < W);

  float t[8];
  if (active) {
    short8 sv = *(const short8*)(row + j0);
#pragma unroll
    for (int e = 0; e < 8; ++e) {
      int jc = j0 + e;
      bool msk = (jc >= cnt_i);
      float raw = bf2f(((const unsigned short*)&sv)[e]);
      t[e] = (msk ? -1e10f : raw) * 0.03125f;
    }
  } else {
#pragma unroll
    for (int e = 0; e < 8; ++e) t[e] = -1e10f * 0.03125f;
  }

  float m = t[0];
#pragma unroll
  for (int e = 1; e < 8; ++e) m = fmaxf(m, t[e]);
#pragma unroll
  for (int o = 32; o > 0; o >>= 1) m = fmaxf(m, __shfl_xor(m, o));
  __shared__ float redm[4], reds[4];
  int wv = tid >> 6, ln = tid & 63;
  if (ln == 0) redm[wv] = m;
  __syncthreads();
  m = fmaxf(fmaxf(redm[0], redm[1]), fmaxf(redm[2], redm[3]));

  float p[8];
  float s = 0.f;
#pragma unroll
  for (int e = 0; e < 8; ++e) {
    p[e] = __expf(t[e] - m);
    s += p[e];
  }
#pragma unroll
  for (int o = 32; o > 0; o >>= 1) s += __shfl_xor(s, o);
  if (ln == 0) reds[wv] = s;
  __syncthreads();
  s = reds[0] + reds[1] + reds[2] + reds[3];
  float inv = 1.0f / s;

  if (active) {
    short8 ov;
#pragma unroll
    for (int e = 0; e < 8; ++e) ((unsigned short*)&ov)[e] = (short)f2bf(p[e] * inv);
    *(short8*)(row + j0) = ov;
  }
}

// ---------------- degenerate-row fixup apply ----------------
__global__ __launch_bounds__(256) void fixup_apply_kernel(const int* __restrict__ cntb,
                                                          const float* __restrict__ fixmean,
                                                          float* __restrict__ out) {
  int b = blockIdx.x, dchunk = blockIdx.y;
  int d = dchunk * 256 + threadIdx.x;
  float val = fixmean[b * 1024 + d];
  for (int i = 0; i < 2048; ++i) {
    if (cntb[b * 2048 + i] != 0) break;
    out[((size_t)b * 2048 + (size_t)i) * 1024 + d] = val;
  }
}

// ---------------- launch ----------------
extern "C" void kernel_launch(void* const* d_in, const int* in_sizes, int n_in,
                              void* d_out, int out_size, void* d_ws, size_t ws_size,
                              hipStream_t stream) {
  const float* x = (const float*)d_in[0];
  const int* pad = (const int*)d_in[1];
  const float* Wq = (const float*)d_in[2];
  const float* bq = (const float*)d_in[3];
  const float* Wk = (const float*)d_in[4];
  const float* bk = (const float*)d_in[5];
  const float* Wv = (const float*)d_in[6];
  const float* bv = (const float*)d_in[7];
  float* out = (float*)d_out;

  char* ws = (char*)d_ws;
  unsigned short* xb  = (unsigned short*)(ws + 0);           // 32MB [16384,1024]
  unsigned short* xc  = (unsigned short*)(ws + 33554432);    // 32MB [8,2048,1024]
  unsigned short* wb  = (unsigned short*)(ws + 67108864);    // 6MB  [3072,1024] = Wq;Wk;Wv
  int*   jmap    = (int*)(ws + 73400320);                    // 64KB
  int*   cntb    = (int*)(ws + 73465856);                    // 64KB
  float* mean_x  = (float*)(ws + 73531392);                  // 32KB
  float* fixmean = (float*)(ws + 73564160);                  // 32KB
  unsigned short* qb  = (unsigned short*)(ws + 75497472);    // 32MB [16384,1024]
  unsigned short* vtc = (unsigned short*)(ws + 109051904);   // 32MB [8,1024,2048]
  unsigned short* sp  = (unsigned short*)(ws + 142606336);   // 64MB [8,2048,2048]
  unsigned short* kcb = (unsigned short*)(ws + 209715200);   // 32MB [8,2048,1024]

  // compaction metadata first (only needs pad)
  compact_kernel<<<8, 256, 0, stream>>>(pad, jmap, cntb, mean_x);

  // converts + fused x scatter (+ xc zero-fill)
  cvtW_kernel<<<3072, 256, 0, stream>>>(Wq, Wk, Wv, wb);
  dim3 gp(2048, 8);
  prep_kernel<<<gp, 256, 0, stream>>>(x, pad, cntb, xb, xc);
  dim3 gmx(32, 8);
  meanx_kernel<<<gmx, 256, 0, stream>>>(xb, mean_x);

  // fused projection: q (from xb) | k,v (from xc, compacted) — one 3072-block dispatch
  dim3 g1(24, 128, 1);
  gemm_bt_kernel<0><<<g1, 256, 0, stream>>>(xb, xc, wb, bq, bk, bv, qb, vtc, kcb, cntb,
                                            1024, 1024, 1024, 1024, 0, 0, 0);

  // fixmean GEMV (needs wb alive)
  dim3 g3(8, 4);
  gemv_kernel<<<g3, 256, 0, stream>>>(mean_x, wb + 2097152, bv, fixmean);

  // scores[b] = q_b @ kc_b^T (128x128 tiles, compacted-causal tile-skip)
  dim3 g4(16, 16, 8);
  gemm_bt_kernel<1><<<g4, 256, 0, stream>>>(qb, nullptr, kcb, nullptr, nullptr, nullptr,
                                            sp, nullptr, nullptr, cntb,
                                            1024, 1024, 1024, 2048, 2097152, 2097152, 4194304);

  // compacted masked softmax (in place)
  dim3 g5(2048, 8);
  softmax_kernel<<<g5, 256, 0, stream>>>(sp, cntb);

  // out[b] = P_b @ Vc_b (128x128 tiles, K-limit roundup64(cnt))
  dim3 g6(8, 16, 8);
  gemm_bt_kernel<2><<<g6, 256, 0, stream>>>(sp, nullptr, vtc, nullptr, nullptr, nullptr,
                                            out, nullptr, nullptr, cntb,
                                            2048, 2048, 2048, 1024, 4194304, 2097152, 2097152);

  // degenerate (fully-masked) rows
  fixup_apply_kernel<<<g3, 256, 0, stream>>>(cntb, fixmean, out);
}

// Round 11
// 292.317 us; speedup vs baseline: 1.4612x; 1.4612x over previous
//
#include <hip/hip_runtime.h>

typedef __attribute__((ext_vector_type(8))) short short8;
typedef __attribute__((ext_vector_type(4))) short short4v;
typedef __attribute__((ext_vector_type(4))) float float4v;

typedef const __attribute__((address_space(1))) unsigned int* gptr_t;
typedef __attribute__((address_space(3))) unsigned int* lptr_t;

__device__ __forceinline__ unsigned short f2bf(float f) {
  unsigned u = __float_as_uint(f);
  u += 0x7FFFu + ((u >> 16) & 1u);
  return (unsigned short)(u >> 16);
}
__device__ __forceinline__ float bf2f(unsigned short h) {
  return __uint_as_float(((unsigned)h) << 16);
}

// ---------------- weights f32 -> bf16 (all three in one dispatch) ----------------
__global__ __launch_bounds__(256) void cvtW_kernel(const float* __restrict__ Wq,
                                                   const float* __restrict__ Wk,
                                                   const float* __restrict__ Wv,
                                                   unsigned short* __restrict__ wb) {
  int blk = blockIdx.x;
  int r = blk >> 10;
  const float* src = (r == 0) ? Wq : ((r == 1) ? Wk : Wv);
  int t = threadIdx.x;
  int i = (blk & 1023) * 256 + t;
  float4v v = ((const float4v*)src)[i];
  short4v o;
  o[0] = (short)f2bf(v[0]);
  o[1] = (short)f2bf(v[1]);
  o[2] = (short)f2bf(v[2]);
  o[3] = (short)f2bf(v[3]);
  ((short4v*)(wb + (size_t)r * 1048576u))[i] = o;
}

// ---------------- pad-mask compaction: prefix counts + index map (+ zero mean_x) ----------------
__global__ __launch_bounds__(256) void compact_kernel(const int* __restrict__ pad,
                                                      int* __restrict__ jmap,
                                                      int* __restrict__ cntb,
                                                      float* __restrict__ mean_x) {
  int b = blockIdx.x;
  const int* prow = pad + b * 2048;
  int t = threadIdx.x;
  float4v z = {0.f, 0.f, 0.f, 0.f};
  ((float4v*)(mean_x + b * 1024))[t] = z;
  int base = t * 8;
  int ind[8], incl[8];
  int s = 0;
#pragma unroll
  for (int e = 0; e < 8; ++e) {
    ind[e] = (prow[base + e] == 0);
    s += ind[e];
    incl[e] = s;
  }
  int lane = t & 63, wv = t >> 6;
  int v = s;
#pragma unroll
  for (int off = 1; off < 64; off <<= 1) {
    int u = __shfl_up(v, off);
    if (lane >= off) v += u;
  }
  __shared__ int wsum[4];
  if (lane == 63) wsum[wv] = v;
  __syncthreads();
  int wbase = 0;
  for (int w = 0; w < wv; ++w) wbase += wsum[w];
  int excl_base = wbase + v - s;
#pragma unroll
  for (int e = 0; e < 8; ++e) {
    int cnt_i = excl_base + incl[e];
    cntb[b * 2048 + base + e] = cnt_i;
    if (ind[e]) jmap[b * 2048 + cnt_i - 1] = base + e;
  }
}

// ---------------- fused x convert + compacted scatter + xc pad-row zero-fill ----------------
__global__ __launch_bounds__(256) void prep_kernel(const float* __restrict__ x,
                                                   const int* __restrict__ pad,
                                                   const int* __restrict__ cntb,
                                                   unsigned short* __restrict__ xb,
                                                   unsigned short* __restrict__ xc) {
  int i = blockIdx.x, b = blockIdx.y;
  int idx = b * 2048 + i;
  int t = threadIdx.x;
  float4v v = ((const float4v*)(x + (size_t)idx * 1024))[t];
  short4v o;
  o[0] = (short)f2bf(v[0]);
  o[1] = (short)f2bf(v[1]);
  o[2] = (short)f2bf(v[2]);
  o[3] = (short)f2bf(v[3]);
  ((short4v*)(xb + (size_t)idx * 1024))[t] = o;
  if (pad[idx] == 0) {
    int jc = cntb[idx] - 1;
    ((short4v*)(xc + ((size_t)(b * 2048 + jc)) * 1024))[t] = o;
  }
  // zero-fill xc rows [Nc, roundup128(Nc)) — row index i reused as the fill target
  int Nc = cntb[b * 2048 + 2047];
  if (i >= Nc && i < ((Nc + 127) & ~127)) {
    short4v z = {0, 0, 0, 0};
    ((short4v*)(xc + ((size_t)(b * 2048 + i)) * 1024))[t] = z;
  }
}

// ---------------- column-sum of xb per batch (coalesced row-major reads) ----------------
__global__ __launch_bounds__(256) void meanx_kernel(const unsigned short* __restrict__ xb,
                                                    float* __restrict__ mean_x) {
  int iblk = blockIdx.x, b = blockIdx.y;
  int t = threadIdx.x;
  const unsigned short* base = xb + ((size_t)b * 2048 + (size_t)iblk * 64) * 1024 + t * 4;
  float s0 = 0.f, s1 = 0.f, s2 = 0.f, s3 = 0.f;
  for (int r = 0; r < 64; ++r) {
    short4v v = *(const short4v*)(base + (size_t)r * 1024);
    s0 += bf2f(((const unsigned short*)&v)[0]);
    s1 += bf2f(((const unsigned short*)&v)[1]);
    s2 += bf2f(((const unsigned short*)&v)[2]);
    s3 += bf2f(((const unsigned short*)&v)[3]);
  }
  float* mp = mean_x + b * 1024 + t * 4;
  atomicAdd(mp + 0, s0);
  atomicAdd(mp + 1, s1);
  atomicAdd(mp + 2, s2);
  atomicAdd(mp + 3, s3);
}

// ---------------- fixmean = mean_x/2048 @ Wv^T + bv ----------------
__global__ __launch_bounds__(256) void gemv_kernel(const float* __restrict__ mean_x,
                                                   const unsigned short* __restrict__ wv,
                                                   const float* __restrict__ bv,
                                                   float* __restrict__ fixmean) {
  int b = blockIdx.x, dblk = blockIdx.y;
  int d = dblk * 256 + threadIdx.x;
  const unsigned short* wrow = wv + (size_t)d * 1024;
  const float* mx = mean_x + b * 1024;
  float s = 0.f;
  for (int h = 0; h < 1024; h += 8) {
    short8 w = *(const short8*)(wrow + h);
#pragma unroll
    for (int e = 0; e < 8; ++e) s += mx[h + e] * bf2f(((const unsigned short*)&w)[e]);
  }
  fixmean[b * 1024 + d] = s * (1.0f / 2048.0f) + bv[d];
}

// ---------------- bf16 GEMM, C = A @ B^T (round-6 exact engine, 4 waves, 128x128) ----------------
// MODE 0: fused projection q|k|v, grid (24,128), XCD-swizzled
// MODE 1: qk : bf16 out, compacted-causal tile-skip, grid (16,16,8)
// MODE 2: pv : f32 out, K-limit roundup64(cnt), grid (8,16,8)
// NOTE: __launch_bounds__(256,4) — do NOT raise the 2nd arg; (256,5) forces VGPR 60->48
// and halves the rate (round-10 measured regression 101->188us on the proj dispatch).
template <int MODE>
__global__ __launch_bounds__(256, 4) void gemm_bt_kernel(
    const unsigned short* __restrict__ A, const unsigned short* __restrict__ A2,
    const unsigned short* __restrict__ B,
    const float* __restrict__ b1, const float* __restrict__ b2, const float* __restrict__ b3,
    void* __restrict__ C, unsigned short* __restrict__ C2, unsigned short* __restrict__ C3,
    const int* __restrict__ cnt,
    int K, int lda, int ldb, int ldc, size_t sA, size_t sB, size_t sC) {
  int bx = blockIdx.x, by = blockIdx.y, bz = blockIdx.z;
  const unsigned short* Aptr = A;
  if (MODE == 0) {  // nwg = 24*128 = 3072, bijective XCD swizzle
    int wg = by * 24 + bx;
    int s = (wg & 7) * 384 + (wg >> 3);
    bx = s % 24;
    by = s / 24;
    int r = bx >> 3;
    if (r > 0) {
      int b = by >> 4;
      if (((by & 15) << 7) >= cnt[(b << 11) + 2047]) return;
      Aptr = A2;
    }
  }
  int Kend = K;
  if (MODE == 1) {
    int tc = cnt[(bz << 11) + (by * 128 + 127)];
    if (bx * 128 >= tc) return;
  }
  if (MODE == 2) {
    int tc = cnt[(bz << 11) + (by * 128 + 127)];
    Kend = (tc + 63) & ~63;
  }

  __shared__ __align__(16) char lds[32768];
  char* ldsA = lds;
  char* ldsB = lds + 16384;

  int tid = threadIdx.x;
  int wave = tid >> 6, lane = tid & 63;
  int lm = lane & 15, g = lane >> 4;
  int wm = wave >> 1, wn = wave & 1;
  int swl = (lm & 7) << 4;

  float4v acc[4][4];
#pragma unroll
  for (int i = 0; i < 4; ++i)
#pragma unroll
    for (int j = 0; j < 4; ++j) {
      float4v z = {0.f, 0.f, 0.f, 0.f};
      acc[i][j] = z;
    }

  const char* Abase = (const char*)(Aptr + sA * (size_t)bz + (size_t)(by * 128) * (size_t)lda);
  const char* Bbase = (const char*)(B + sB * (size_t)bz + (size_t)(bx * 128) * (size_t)ldb);
  size_t strideA = (size_t)lda * 2u;
  size_t strideB = (size_t)ldb * 2u;

  int Lbase = wave * 1024 + lane * 16;

  for (int kt = 0; kt < Kend; kt += 64) {
#pragma unroll
    for (int c = 0; c < 4; ++c) {
      int L = c * 4096 + Lbase;
      int row = L >> 7;
      int lb = (L & 127) ^ ((row & 7) << 4);  // inverse-swizzled source byte within row
      const char* ga = Abase + (size_t)row * strideA + (size_t)(kt * 2) + lb;
      __builtin_amdgcn_global_load_lds((gptr_t)(const void*)ga,
                                       (lptr_t)(void*)(ldsA + c * 4096 + wave * 1024), 16, 0, 0);
      const char* gb = Bbase + (size_t)row * strideB + (size_t)(kt * 2) + lb;
      __builtin_amdgcn_global_load_lds((gptr_t)(const void*)gb,
                                       (lptr_t)(void*)(ldsB + c * 4096 + wave * 1024), 16, 0, 0);
    }
    __syncthreads();

#pragma unroll
    for (int k0 = 0; k0 < 64; k0 += 32) {
      short8 af[4], bfv[4];
      int b0 = (k0 * 2 + 16 * g) ^ swl;  // contiguous 16B k-chunk (self-consistent permutation)
#pragma unroll
      for (int mi = 0; mi < 4; ++mi) {
        const char* p = ldsA + (wm * 64 + mi * 16 + lm) * 128;
        af[mi] = *(const short8*)(p + b0);
      }
#pragma unroll
      for (int ni = 0; ni < 4; ++ni) {
        const char* p = ldsB + (wn * 64 + ni * 16 + lm) * 128;
        bfv[ni] = *(const short8*)(p + b0);
      }
#pragma unroll
      for (int mi = 0; mi < 4; ++mi)
#pragma unroll
        for (int ni = 0; ni < 4; ++ni)
          acc[mi][ni] =
              __builtin_amdgcn_mfma_f32_16x16x32_bf16(af[mi], bfv[ni], acc[mi][ni], 0, 0, 0);
    }
    __syncthreads();
  }

  // epilogue: C/D layout col = lane&15, row = (lane>>4)*4 + r   [m89-verified]
  int mb = by * 128 + wm * 64 + g * 4;
  int nb = bx * 128 + wn * 64 + lm;
#pragma unroll
  for (int mi = 0; mi < 4; ++mi) {
#pragma unroll
    for (int ni = 0; ni < 4; ++ni) {
      int n = nb + ni * 16;
      float bias = 0.0f;
      if (MODE == 0) {
        int nn = n & 1023;
        int r = n >> 10;
        bias = (r == 0) ? b1[nn] : ((r == 1) ? b2[nn] : b3[nn]);
      }
#pragma unroll
      for (int r4 = 0; r4 < 4; ++r4) {
        int m = mb + mi * 16 + r4;
        float v = acc[mi][ni][r4] + bias;
        if (MODE == 0) {
          int nn = n & 1023;
          int r = n >> 10;
          if (r == 0) {
            ((unsigned short*)C)[(size_t)m * 1024u + nn] = f2bf(v);
          } else if (r == 1) {
            C3[(size_t)m * 1024u + nn] = f2bf(v);
          } else {
            size_t idx = ((size_t)(m >> 11) << 21) + ((size_t)nn << 11) + (size_t)(m & 2047);
            C2[idx] = f2bf(v);
          }
        } else if (MODE == 1) {
          ((unsigned short*)C)[sC * (size_t)bz + (size_t)m * (size_t)ldc + n] = f2bf(v);
        } else {
          ((float*)C)[sC * (size_t)bz + (size_t)m * (size_t)ldc + n] = v;
        }
      }
    }
  }
}

// ---------------- compacted masked softmax, in-place on bf16 scores ----------------
__global__ __launch_bounds__(256) void softmax_kernel(unsigned short* __restrict__ sp,
                                                      const int* __restrict__ cntb) {
  int i = blockIdx.x, b = blockIdx.y;
  int cnt_i = cntb[b * 2048 + i];
  int tcnt = cntb[b * 2048 + (i | 127)];
  int W = (tcnt + 63) & ~63;
  unsigned short* row = sp + ((size_t)b * 2048 + (size_t)i) * 2048;
  int tid = threadIdx.x;
  int j0 = tid * 8;
  bool active = (j0 < W);

  float t[8];
  if (active) {
    short8 sv = *(const short8*)(row + j0);
#pragma unroll
    for (int e = 0; e < 8; ++e) {
      int jc = j0 + e;
      bool msk = (jc >= cnt_i);
      float raw = bf2f(((const unsigned short*)&sv)[e]);
      t[e] = (msk ? -1e10f : raw) * 0.03125f;
    }
  } else {
#pragma unroll
    for (int e = 0; e < 8; ++e) t[e] = -1e10f * 0.03125f;
  }

  float m = t[0];
#pragma unroll
  for (int e = 1; e < 8; ++e) m = fmaxf(m, t[e]);
#pragma unroll
  for (int o = 32; o > 0; o >>= 1) m = fmaxf(m, __shfl_xor(m, o));
  __shared__ float redm[4], reds[4];
  int wv = tid >> 6, ln = tid & 63;
  if (ln == 0) redm[wv] = m;
  __syncthreads();
  m = fmaxf(fmaxf(redm[0], redm[1]), fmaxf(redm[2], redm[3]));

  float p[8];
  float s = 0.f;
#pragma unroll
  for (int e = 0; e < 8; ++e) {
    p[e] = __expf(t[e] - m);
    s += p[e];
  }
#pragma unroll
  for (int o = 32; o > 0; o >>= 1) s += __shfl_xor(s, o);
  if (ln == 0) reds[wv] = s;
  __syncthreads();
  s = reds[0] + reds[1] + reds[2] + reds[3];
  float inv = 1.0f / s;

  if (active) {
    short8 ov;
#pragma unroll
    for (int e = 0; e < 8; ++e) ((unsigned short*)&ov)[e] = (short)f2bf(p[e] * inv);
    *(short8*)(row + j0) = ov;
  }
}

// ---------------- degenerate-row fixup apply ----------------
__global__ __launch_bounds__(256) void fixup_apply_kernel(const int* __restrict__ cntb,
                                                          const float* __restrict__ fixmean,
                                                          float* __restrict__ out) {
  int b = blockIdx.x, dchunk = blockIdx.y;
  int d = dchunk * 256 + threadIdx.x;
  float val = fixmean[b * 1024 + d];
  for (int i = 0; i < 2048; ++i) {
    if (cntb[b * 2048 + i] != 0) break;
    out[((size_t)b * 2048 + (size_t)i) * 1024 + d] = val;
  }
}

// ---------------- launch ----------------
extern "C" void kernel_launch(void* const* d_in, const int* in_sizes, int n_in,
                              void* d_out, int out_size, void* d_ws, size_t ws_size,
                              hipStream_t stream) {
  const float* x = (const float*)d_in[0];
  const int* pad = (const int*)d_in[1];
  const float* Wq = (const float*)d_in[2];
  const float* bq = (const float*)d_in[3];
  const float* Wk = (const float*)d_in[4];
  const float* bk = (const float*)d_in[5];
  const float* Wv = (const float*)d_in[6];
  const float* bv = (const float*)d_in[7];
  float* out = (float*)d_out;

  char* ws = (char*)d_ws;
  unsigned short* xb  = (unsigned short*)(ws + 0);           // 32MB [16384,1024]
  unsigned short* xc  = (unsigned short*)(ws + 33554432);    // 32MB [8,2048,1024]
  unsigned short* wb  = (unsigned short*)(ws + 67108864);    // 6MB  [3072,1024] = Wq;Wk;Wv
  int*   jmap    = (int*)(ws + 73400320);                    // 64KB
  int*   cntb    = (int*)(ws + 73465856);                    // 64KB
  float* mean_x  = (float*)(ws + 73531392);                  // 32KB
  float* fixmean = (float*)(ws + 73564160);                  // 32KB
  unsigned short* qb  = (unsigned short*)(ws + 75497472);    // 32MB [16384,1024]
  unsigned short* vtc = (unsigned short*)(ws + 109051904);   // 32MB [8,1024,2048]
  unsigned short* sp  = (unsigned short*)(ws + 142606336);   // 64MB [8,2048,2048]
  unsigned short* kcb = (unsigned short*)(ws + 209715200);   // 32MB [8,2048,1024]

  // compaction metadata first (only needs pad)
  compact_kernel<<<8, 256, 0, stream>>>(pad, jmap, cntb, mean_x);

  // converts + fused x scatter (+ xc zero-fill)
  cvtW_kernel<<<3072, 256, 0, stream>>>(Wq, Wk, Wv, wb);
  dim3 gp(2048, 8);
  prep_kernel<<<gp, 256, 0, stream>>>(x, pad, cntb, xb, xc);
  dim3 gmx(32, 8);
  meanx_kernel<<<gmx, 256, 0, stream>>>(xb, mean_x);

  // fused projection: q (from xb) | k,v (from xc, compacted) — one 3072-block dispatch
  dim3 g1(24, 128, 1);
  gemm_bt_kernel<0><<<g1, 256, 0, stream>>>(xb, xc, wb, bq, bk, bv, qb, vtc, kcb, cntb,
                                            1024, 1024, 1024, 1024, 0, 0, 0);

  // fixmean GEMV (needs wb alive)
  dim3 g3(8, 4);
  gemv_kernel<<<g3, 256, 0, stream>>>(mean_x, wb + 2097152, bv, fixmean);

  // scores[b] = q_b @ kc_b^T (128x128 tiles, compacted-causal tile-skip)
  dim3 g4(16, 16, 8);
  gemm_bt_kernel<1><<<g4, 256, 0, stream>>>(qb, nullptr, kcb, nullptr, nullptr, nullptr,
                                            sp, nullptr, nullptr, cntb,
                                            1024, 1024, 1024, 2048, 2097152, 2097152, 4194304);

  // compacted masked softmax (in place)
  dim3 g5(2048, 8);
  softmax_kernel<<<g5, 256, 0, stream>>>(sp, cntb);

  // out[b] = P_b @ Vc_b (128x128 tiles, K-limit roundup64(cnt))
  dim3 g6(8, 16, 8);
  gemm_bt_kernel<2><<<g6, 256, 0, stream>>>(sp, nullptr, vtc, nullptr, nullptr, nullptr,
                                            out, nullptr, nullptr, cntb,
                                            2048, 2048, 2048, 1024, 4194304, 2097152, 2097152);

  // degenerate (fully-masked) rows
  fixup_apply_kernel<<<g3, 256, 0, stream>>>(cntb, fixmean, out);
}

// Round 12
// 268.479 us; speedup vs baseline: 1.5909x; 1.0888x over previous
//
#include <hip/hip_runtime.h>

typedef __attribute__((ext_vector_type(8))) short short8;
typedef __attribute__((ext_vector_type(4))) short short4v;
typedef __attribute__((ext_vector_type(4))) float float4v;

typedef const __attribute__((address_space(1))) unsigned int* gptr_t;
typedef __attribute__((address_space(3))) unsigned int* lptr_t;

__device__ __forceinline__ unsigned short f2bf(float f) {
  unsigned u = __float_as_uint(f);
  u += 0x7FFFu + ((u >> 16) & 1u);
  return (unsigned short)(u >> 16);
}
__device__ __forceinline__ float bf2f(unsigned short h) {
  return __uint_as_float(((unsigned)h) << 16);
}

// ---------------- weights f32 -> bf16 (all three in one dispatch) ----------------
__global__ __launch_bounds__(256) void cvtW_kernel(const float* __restrict__ Wq,
                                                   const float* __restrict__ Wk,
                                                   const float* __restrict__ Wv,
                                                   unsigned short* __restrict__ wb) {
  int blk = blockIdx.x;
  int r = blk >> 10;
  const float* src = (r == 0) ? Wq : ((r == 1) ? Wk : Wv);
  int t = threadIdx.x;
  int i = (blk & 1023) * 256 + t;
  float4v v = ((const float4v*)src)[i];
  short4v o;
  o[0] = (short)f2bf(v[0]);
  o[1] = (short)f2bf(v[1]);
  o[2] = (short)f2bf(v[2]);
  o[3] = (short)f2bf(v[3]);
  ((short4v*)(wb + (size_t)r * 1048576u))[i] = o;
}

// ---------------- pad-mask compaction: prefix counts + index map (+ zero mean_x) ----------------
__global__ __launch_bounds__(256) void compact_kernel(const int* __restrict__ pad,
                                                      int* __restrict__ jmap,
                                                      int* __restrict__ cntb,
                                                      float* __restrict__ mean_x) {
  int b = blockIdx.x;
  const int* prow = pad + b * 2048;
  int t = threadIdx.x;
  float4v z = {0.f, 0.f, 0.f, 0.f};
  ((float4v*)(mean_x + b * 1024))[t] = z;
  int base = t * 8;
  int ind[8], incl[8];
  int s = 0;
#pragma unroll
  for (int e = 0; e < 8; ++e) {
    ind[e] = (prow[base + e] == 0);
    s += ind[e];
    incl[e] = s;
  }
  int lane = t & 63, wv = t >> 6;
  int v = s;
#pragma unroll
  for (int off = 1; off < 64; off <<= 1) {
    int u = __shfl_up(v, off);
    if (lane >= off) v += u;
  }
  __shared__ int wsum[4];
  if (lane == 63) wsum[wv] = v;
  __syncthreads();
  int wbase = 0;
  for (int w = 0; w < wv; ++w) wbase += wsum[w];
  int excl_base = wbase + v - s;
#pragma unroll
  for (int e = 0; e < 8; ++e) {
    int cnt_i = excl_base + incl[e];
    cntb[b * 2048 + base + e] = cnt_i;
    if (ind[e]) jmap[b * 2048 + cnt_i - 1] = base + e;
  }
}

// ---------------- fused x convert + compacted scatter + xc pad-row zero-fill ----------------
__global__ __launch_bounds__(256) void prep_kernel(const float* __restrict__ x,
                                                   const int* __restrict__ pad,
                                                   const int* __restrict__ cntb,
                                                   unsigned short* __restrict__ xb,
                                                   unsigned short* __restrict__ xc) {
  int i = blockIdx.x, b = blockIdx.y;
  int idx = b * 2048 + i;
  int t = threadIdx.x;
  float4v v = ((const float4v*)(x + (size_t)idx * 1024))[t];
  short4v o;
  o[0] = (short)f2bf(v[0]);
  o[1] = (short)f2bf(v[1]);
  o[2] = (short)f2bf(v[2]);
  o[3] = (short)f2bf(v[3]);
  ((short4v*)(xb + (size_t)idx * 1024))[t] = o;
  if (pad[idx] == 0) {
    int jc = cntb[idx] - 1;
    ((short4v*)(xc + ((size_t)(b * 2048 + jc)) * 1024))[t] = o;
  }
  // zero-fill xc rows [Nc, roundup128(Nc)) — row index i reused as the fill target
  int Nc = cntb[b * 2048 + 2047];
  if (i >= Nc && i < ((Nc + 127) & ~127)) {
    short4v z = {0, 0, 0, 0};
    ((short4v*)(xc + ((size_t)(b * 2048 + i)) * 1024))[t] = z;
  }
}

// ---------------- column-sum of xb per batch (coalesced row-major reads) ----------------
__global__ __launch_bounds__(256) void meanx_kernel(const unsigned short* __restrict__ xb,
                                                    float* __restrict__ mean_x) {
  int iblk = blockIdx.x, b = blockIdx.y;
  int t = threadIdx.x;
  const unsigned short* base = xb + ((size_t)b * 2048 + (size_t)iblk * 64) * 1024 + t * 4;
  float s0 = 0.f, s1 = 0.f, s2 = 0.f, s3 = 0.f;
  for (int r = 0; r < 64; ++r) {
    short4v v = *(const short4v*)(base + (size_t)r * 1024);
    s0 += bf2f(((const unsigned short*)&v)[0]);
    s1 += bf2f(((const unsigned short*)&v)[1]);
    s2 += bf2f(((const unsigned short*)&v)[2]);
    s3 += bf2f(((const unsigned short*)&v)[3]);
  }
  float* mp = mean_x + b * 1024 + t * 4;
  atomicAdd(mp + 0, s0);
  atomicAdd(mp + 1, s1);
  atomicAdd(mp + 2, s2);
  atomicAdd(mp + 3, s3);
}

// ---------------- bf16 GEMM, C = A @ B^T (round-6 exact engine, 4 waves, 128x128) ----------------
// MODE 0: fused projection q|k|v, grid (24,128), XCD-swizzled
// MODE 1: qk : bf16 out, compacted-causal tile-skip, grid (16,16,8), per-z XCD swizzle
// MODE 2: pv : f32 out, K-limit roundup64(cnt), grid (8,16,8), per-z XCD swizzle
// NOTE: __launch_bounds__(256,4) — do NOT raise the 2nd arg; (256,5) forces VGPR 60->48
// and halves the rate (round-10 measured regression 101->188us on the proj dispatch).
template <int MODE>
__global__ __launch_bounds__(256, 4) void gemm_bt_kernel(
    const unsigned short* __restrict__ A, const unsigned short* __restrict__ A2,
    const unsigned short* __restrict__ B,
    const float* __restrict__ b1, const float* __restrict__ b2, const float* __restrict__ b3,
    void* __restrict__ C, unsigned short* __restrict__ C2, unsigned short* __restrict__ C3,
    const int* __restrict__ cnt,
    int K, int lda, int ldb, int ldc, size_t sA, size_t sB, size_t sC) {
  int bx = blockIdx.x, by = blockIdx.y, bz = blockIdx.z;
  const unsigned short* Aptr = A;
  if (MODE == 0) {  // nwg = 24*128 = 3072, bijective XCD swizzle
    int wg = by * 24 + bx;
    int s = (wg & 7) * 384 + (wg >> 3);
    bx = s % 24;
    by = s / 24;
    int r = bx >> 3;
    if (r > 0) {
      int b = by >> 4;
      if (((by & 15) << 7) >= cnt[(b << 11) + 2047]) return;
      Aptr = A2;
    }
  }
  if (MODE == 1) {  // per-z-slice nwg = 256: chunks of 32 wg (2 by-rows) per XCD
    int wg = by * 16 + bx;
    int s = (wg & 7) * 32 + (wg >> 3);
    bx = s & 15;
    by = s >> 4;
  }
  if (MODE == 2) {  // per-z-slice nwg = 128: chunks of 16 wg (2 by-rows) per XCD
    int wg = by * 8 + bx;
    int s = (wg & 7) * 16 + (wg >> 3);
    bx = s & 7;
    by = s >> 3;
  }
  int Kend = K;
  if (MODE == 1) {
    int tc = cnt[(bz << 11) + (by * 128 + 127)];
    if (bx * 128 >= tc) return;
  }
  if (MODE == 2) {
    int tc = cnt[(bz << 11) + (by * 128 + 127)];
    Kend = (tc + 63) & ~63;
  }

  __shared__ __align__(16) char lds[32768];
  char* ldsA = lds;
  char* ldsB = lds + 16384;

  int tid = threadIdx.x;
  int wave = tid >> 6, lane = tid & 63;
  int lm = lane & 15, g = lane >> 4;
  int wm = wave >> 1, wn = wave & 1;
  int swl = (lm & 7) << 4;

  float4v acc[4][4];
#pragma unroll
  for (int i = 0; i < 4; ++i)
#pragma unroll
    for (int j = 0; j < 4; ++j) {
      float4v z = {0.f, 0.f, 0.f, 0.f};
      acc[i][j] = z;
    }

  const char* Abase = (const char*)(Aptr + sA * (size_t)bz + (size_t)(by * 128) * (size_t)lda);
  const char* Bbase = (const char*)(B + sB * (size_t)bz + (size_t)(bx * 128) * (size_t)ldb);
  size_t strideA = (size_t)lda * 2u;
  size_t strideB = (size_t)ldb * 2u;

  int Lbase = wave * 1024 + lane * 16;

  for (int kt = 0; kt < Kend; kt += 64) {
#pragma unroll
    for (int c = 0; c < 4; ++c) {
      int L = c * 4096 + Lbase;
      int row = L >> 7;
      int lb = (L & 127) ^ ((row & 7) << 4);  // inverse-swizzled source byte within row
      const char* ga = Abase + (size_t)row * strideA + (size_t)(kt * 2) + lb;
      __builtin_amdgcn_global_load_lds((gptr_t)(const void*)ga,
                                       (lptr_t)(void*)(ldsA + c * 4096 + wave * 1024), 16, 0, 0);
      const char* gb = Bbase + (size_t)row * strideB + (size_t)(kt * 2) + lb;
      __builtin_amdgcn_global_load_lds((gptr_t)(const void*)gb,
                                       (lptr_t)(void*)(ldsB + c * 4096 + wave * 1024), 16, 0, 0);
    }
    __syncthreads();

#pragma unroll
    for (int k0 = 0; k0 < 64; k0 += 32) {
      short8 af[4], bfv[4];
      int b0 = (k0 * 2 + 16 * g) ^ swl;  // contiguous 16B k-chunk (self-consistent permutation)
#pragma unroll
      for (int mi = 0; mi < 4; ++mi) {
        const char* p = ldsA + (wm * 64 + mi * 16 + lm) * 128;
        af[mi] = *(const short8*)(p + b0);
      }
#pragma unroll
      for (int ni = 0; ni < 4; ++ni) {
        const char* p = ldsB + (wn * 64 + ni * 16 + lm) * 128;
        bfv[ni] = *(const short8*)(p + b0);
      }
#pragma unroll
      for (int mi = 0; mi < 4; ++mi)
#pragma unroll
        for (int ni = 0; ni < 4; ++ni)
          acc[mi][ni] =
              __builtin_amdgcn_mfma_f32_16x16x32_bf16(af[mi], bfv[ni], acc[mi][ni], 0, 0, 0);
    }
    __syncthreads();
  }

  // epilogue: C/D layout col = lane&15, row = (lane>>4)*4 + r   [m89-verified]
  int mb = by * 128 + wm * 64 + g * 4;
  int nb = bx * 128 + wn * 64 + lm;
#pragma unroll
  for (int mi = 0; mi < 4; ++mi) {
#pragma unroll
    for (int ni = 0; ni < 4; ++ni) {
      int n = nb + ni * 16;
      float bias = 0.0f;
      if (MODE == 0) {
        int nn = n & 1023;
        int r = n >> 10;
        bias = (r == 0) ? b1[nn] : ((r == 1) ? b2[nn] : b3[nn]);
      }
#pragma unroll
      for (int r4 = 0; r4 < 4; ++r4) {
        int m = mb + mi * 16 + r4;
        float v = acc[mi][ni][r4] + bias;
        if (MODE == 0) {
          int nn = n & 1023;
          int r = n >> 10;
          if (r == 0) {
            ((unsigned short*)C)[(size_t)m * 1024u + nn] = f2bf(v);
          } else if (r == 1) {
            C3[(size_t)m * 1024u + nn] = f2bf(v);
          } else {
            size_t idx = ((size_t)(m >> 11) << 21) + ((size_t)nn << 11) + (size_t)(m & 2047);
            C2[idx] = f2bf(v);
          }
        } else if (MODE == 1) {
          ((unsigned short*)C)[sC * (size_t)bz + (size_t)m * (size_t)ldc + n] = f2bf(v);
        } else {
          ((float*)C)[sC * (size_t)bz + (size_t)m * (size_t)ldc + n] = v;
        }
      }
    }
  }
}

// ---------------- compacted masked softmax, in-place on bf16 scores ----------------
__global__ __launch_bounds__(256) void softmax_kernel(unsigned short* __restrict__ sp,
                                                      const int* __restrict__ cntb) {
  int i = blockIdx.x, b = blockIdx.y;
  int cnt_i = cntb[b * 2048 + i];
  int tcnt = cntb[b * 2048 + (i | 127)];
  int W = (tcnt + 63) & ~63;
  unsigned short* row = sp + ((size_t)b * 2048 + (size_t)i) * 2048;
  int tid = threadIdx.x;
  int j0 = tid * 8;
  bool active = (j0 < W);

  float t[8];
  if (active) {
    short8 sv = *(const short8*)(row + j0);
#pragma unroll
    for (int e = 0; e < 8; ++e) {
      int jc = j0 + e;
      bool msk = (jc >= cnt_i);
      float raw = bf2f(((const unsigned short*)&sv)[e]);
      t[e] = (msk ? -1e10f : raw) * 0.03125f;
    }
  } else {
#pragma unroll
    for (int e = 0; e < 8; ++e) t[e] = -1e10f * 0.03125f;
  }

  float m = t[0];
#pragma unroll
  for (int e = 1; e < 8; ++e) m = fmaxf(m, t[e]);
#pragma unroll
  for (int o = 32; o > 0; o >>= 1) m = fmaxf(m, __shfl_xor(m, o));
  __shared__ float redm[4], reds[4];
  int wv = tid >> 6, ln = tid & 63;
  if (ln == 0) redm[wv] = m;
  __syncthreads();
  m = fmaxf(fmaxf(redm[0], redm[1]), fmaxf(redm[2], redm[3]));

  float p[8];
  float s = 0.f;
#pragma unroll
  for (int e = 0; e < 8; ++e) {
    p[e] = __expf(t[e] - m);
    s += p[e];
  }
#pragma unroll
  for (int o = 32; o > 0; o >>= 1) s += __shfl_xor(s, o);
  if (ln == 0) reds[wv] = s;
  __syncthreads();
  s = reds[0] + reds[1] + reds[2] + reds[3];
  float inv = 1.0f / s;

  if (active) {
    short8 ov;
#pragma unroll
    for (int e = 0; e < 8; ++e) ((unsigned short*)&ov)[e] = (short)f2bf(p[e] * inv);
    *(short8*)(row + j0) = ov;
  }
}

// ---------------- degenerate-row fixup: gemv (mean_x/2048 @ Wv^T + bv) + apply ----------------
// Only batches with cnt(0)==0 have degenerate rows; early-exit otherwise.
__global__ __launch_bounds__(256) void fixup_kernel(const int* __restrict__ cntb,
                                                    const float* __restrict__ mean_x,
                                                    const unsigned short* __restrict__ wv,
                                                    const float* __restrict__ bv,
                                                    float* __restrict__ out) {
  int b = blockIdx.x, dblk = blockIdx.y;
  if (cntb[b * 2048] != 0) return;  // row 0 unmasked -> no degenerate rows in batch b
  int d = dblk * 256 + threadIdx.x;
  const unsigned short* wrow = wv + (size_t)d * 1024;
  const float* mx = mean_x + b * 1024;
  float s = 0.f;
  for (int h = 0; h < 1024; h += 8) {
    short8 w = *(const short8*)(wrow + h);
#pragma unroll
    for (int e = 0; e < 8; ++e) s += mx[h + e] * bf2f(((const unsigned short*)&w)[e]);
  }
  float val = s * (1.0f / 2048.0f) + bv[d];
  for (int i = 0; i < 2048; ++i) {
    if (cntb[b * 2048 + i] != 0) break;
    out[((size_t)b * 2048 + (size_t)i) * 1024 + d] = val;
  }
}

// ---------------- launch ----------------
extern "C" void kernel_launch(void* const* d_in, const int* in_sizes, int n_in,
                              void* d_out, int out_size, void* d_ws, size_t ws_size,
                              hipStream_t stream) {
  const float* x = (const float*)d_in[0];
  const int* pad = (const int*)d_in[1];
  const float* Wq = (const float*)d_in[2];
  const float* bq = (const float*)d_in[3];
  const float* Wk = (const float*)d_in[4];
  const float* bk = (const float*)d_in[5];
  const float* Wv = (const float*)d_in[6];
  const float* bv = (const float*)d_in[7];
  float* out = (float*)d_out;

  char* ws = (char*)d_ws;
  unsigned short* xb  = (unsigned short*)(ws + 0);           // 32MB [16384,1024]
  unsigned short* xc  = (unsigned short*)(ws + 33554432);    // 32MB [8,2048,1024]
  unsigned short* wb  = (unsigned short*)(ws + 67108864);    // 6MB  [3072,1024] = Wq;Wk;Wv
  int*   jmap    = (int*)(ws + 73400320);                    // 64KB
  int*   cntb    = (int*)(ws + 73465856);                    // 64KB
  float* mean_x  = (float*)(ws + 73531392);                  // 32KB
  unsigned short* qb  = (unsigned short*)(ws + 75497472);    // 32MB [16384,1024]
  unsigned short* vtc = (unsigned short*)(ws + 109051904);   // 32MB [8,1024,2048]
  unsigned short* sp  = (unsigned short*)(ws + 142606336);   // 64MB [8,2048,2048]
  unsigned short* kcb = (unsigned short*)(ws + 209715200);   // 32MB [8,2048,1024]

  // compaction metadata first (only needs pad)
  compact_kernel<<<8, 256, 0, stream>>>(pad, jmap, cntb, mean_x);

  // converts + fused x scatter (+ xc zero-fill)
  cvtW_kernel<<<3072, 256, 0, stream>>>(Wq, Wk, Wv, wb);
  dim3 gp(2048, 8);
  prep_kernel<<<gp, 256, 0, stream>>>(x, pad, cntb, xb, xc);
  dim3 gmx(32, 8);
  meanx_kernel<<<gmx, 256, 0, stream>>>(xb, mean_x);

  // fused projection: q (from xb) | k,v (from xc, compacted) — one 3072-block dispatch
  dim3 g1(24, 128, 1);
  gemm_bt_kernel<0><<<g1, 256, 0, stream>>>(xb, xc, wb, bq, bk, bv, qb, vtc, kcb, cntb,
                                            1024, 1024, 1024, 1024, 0, 0, 0);

  // scores[b] = q_b @ kc_b^T (128x128 tiles, compacted-causal tile-skip, XCD swizzle)
  dim3 g4(16, 16, 8);
  gemm_bt_kernel<1><<<g4, 256, 0, stream>>>(qb, nullptr, kcb, nullptr, nullptr, nullptr,
                                            sp, nullptr, nullptr, cntb,
                                            1024, 1024, 1024, 2048, 2097152, 2097152, 4194304);

  // compacted masked softmax (in place)
  dim3 g5(2048, 8);
  softmax_kernel<<<g5, 256, 0, stream>>>(sp, cntb);

  // out[b] = P_b @ Vc_b (128x128 tiles, K-limit roundup64(cnt), XCD swizzle)
  dim3 g6(8, 16, 8);
  gemm_bt_kernel<2><<<g6, 256, 0, stream>>>(sp, nullptr, vtc, nullptr, nullptr, nullptr,
                                            out, nullptr, nullptr, cntb,
                                            2048, 2048, 2048, 1024, 4194304, 2097152, 2097152);

  // degenerate (fully-masked) rows: fused gemv + apply (needs wb alive)
  dim3 g3(8, 4);
  fixup_kernel<<<g3, 256, 0, stream>>>(cntb, mean_x, wb + 2097152, bv, out);
}